// Round 5
// baseline (993.464 us; speedup 1.0000x reference)
//
#include <hip/hip_runtime.h>

#define D     128
#define NT    200000
#define NL    50000
#define ETA   1000000
#define EREV  1000000
#define ELL   500000
#define ELBL  500000

typedef __attribute__((ext_vector_type(8))) __bf16 bf16x8;
typedef __attribute__((ext_vector_type(4))) float f32x4;
typedef __attribute__((ext_vector_type(2))) _Float16 f16x2;
typedef __attribute__((ext_vector_type(4))) _Float16 f16x4;
typedef __attribute__((ext_vector_type(8))) _Float16 f16x8;

__device__ inline bf16x8 cvt8(float4 a, float4 b)
{
    bf16x8 r;
    r[0] = (__bf16)a.x; r[1] = (__bf16)a.y; r[2] = (__bf16)a.z; r[3] = (__bf16)a.w;
    r[4] = (__bf16)b.x; r[5] = (__bf16)b.y; r[6] = (__bf16)b.z; r[7] = (__bf16)b.w;
    return r;
}

// Build f16x8 from two f32x4 accumulators (for permuted Z stores).
__device__ inline f16x8 pack8(const f32x4& a, const f32x4& b)
{
    f16x8 o;
    o[0] = (_Float16)a[0]; o[1] = (_Float16)a[1];
    o[2] = (_Float16)a[2]; o[3] = (_Float16)a[3];
    o[4] = (_Float16)b[0]; o[5] = (_Float16)b[1];
    o[6] = (_Float16)b[2]; o[7] = (_Float16)b[3];
    return o;
}

// ---------------------------------------------------------------------------
// All Z/mean tables use a PERMUTED per-row layout matching the MFMA C-frag:
//   perm[row][q*32 + nt*4 + i]  ==  logical[row][nt*16 + q*4 + i]
// Elementwise ops (means, dot products) are permutation-invariant as long as
// both operands share the layout.
// ---------------------------------------------------------------------------

__global__ __launch_bounds__(256) void prep_weights(
    const float* __restrict__ Wl_tl, const float* __restrict__ Wr_tl,
    const float* __restrict__ Wl_ll, const float* __restrict__ Wr_ll,
    const float* __restrict__ b_tl, const float* __restrict__ b_ll,
    __bf16* __restrict__ Wb, float* __restrict__ bias_sum)
{
    int i = blockIdx.x * 256 + threadIdx.x;
    if (i < D * D) {
        Wb[i]             = (__bf16)Wl_tl[i];
        Wb[D * D + i]     = (__bf16)Wr_tl[i];
        Wb[2 * D * D + i] = (__bf16)Wl_ll[i];
        Wb[3 * D * D + i] = (__bf16)(Wr_tl[i] + Wr_ll[i]);
    }
    if (i < D) bias_sum[i] = b_tl[i] + b_ll[i];
}

__global__ __launch_bounds__(256) void count_kernel(
    const int* __restrict__ dst, int* __restrict__ cnt, int E)
{
    int e = blockIdx.x * 256 + threadIdx.x;
    if (e >= E) return;
    atomicAdd(&cnt[dst[e]], 1);
}

__global__ __launch_bounds__(256) void alloc_kernel(
    const int* __restrict__ cnt, int* __restrict__ cur,
    int* __restrict__ gcnt, int n)
{
    int i = blockIdx.x * 256 + threadIdx.x;
    int lane = threadIdx.x & 63;
    int deg = (i < n) ? cnt[i] : 0;
    int incl = deg;
#pragma unroll
    for (int off = 1; off < 64; off <<= 1) {
        int v = __shfl_up(incl, off, 64);
        if (lane >= off) incl += v;
    }
    int excl = incl - deg;
    int total = __shfl(incl, 63, 64);
    int base = 0;
    if (lane == 63) base = atomicAdd(gcnt, total);
    base = __shfl(base, 63, 64);
    if (i < n) cur[i] = base + excl;
}

__global__ __launch_bounds__(256) void fill_kernel(
    const int* __restrict__ src, const int* __restrict__ dst,
    int* __restrict__ cur, int* __restrict__ csr, int E)
{
    int e = blockIdx.x * 256 + threadIdx.x;
    if (e >= E) return;
    int pos = atomicAdd(&cur[dst[e]], 1);
    csr[pos] = src[e];
}

// ---------------------------------------------------------------------------
// Segmented mean over a f16[*][128] table. One wave per dst row: per edge the
// wave issues ONE fully-coalesced 256 B load (64 lanes x f16x2). No
// divergence (whole wave shares the row's degree). 4-wide unrolled.
// Output: f16 (outH) or fp32 (outF) in the same (permuted) layout.
// ---------------------------------------------------------------------------
__global__ __launch_bounds__(256) void agg_zmean(
    const _Float16* __restrict__ Z, const int* __restrict__ csr,
    const int* __restrict__ cnt, const int* __restrict__ cur,
    _Float16* __restrict__ outH, float* __restrict__ outF, int n)
{
    int row = blockIdx.x * 4 + (threadIdx.x >> 6);
    if (row >= n) return;
    int lane = threadIdx.x & 63;
    int deg = cnt[row];
    int end = cur[row];
    int e = end - deg;
    float ax = 0.f, ay = 0.f;
    for (; e + 3 < end; e += 4) {
        int s0 = csr[e], s1 = csr[e + 1], s2 = csr[e + 2], s3 = csr[e + 3];
        f16x2 v0 = *reinterpret_cast<const f16x2*>(Z + (size_t)s0 * D + lane * 2);
        f16x2 v1 = *reinterpret_cast<const f16x2*>(Z + (size_t)s1 * D + lane * 2);
        f16x2 v2 = *reinterpret_cast<const f16x2*>(Z + (size_t)s2 * D + lane * 2);
        f16x2 v3 = *reinterpret_cast<const f16x2*>(Z + (size_t)s3 * D + lane * 2);
        ax += (float)v0[0] + (float)v1[0] + (float)v2[0] + (float)v3[0];
        ay += (float)v0[1] + (float)v1[1] + (float)v2[1] + (float)v3[1];
    }
    for (; e < end; ++e) {
        int s0 = csr[e];
        f16x2 v0 = *reinterpret_cast<const f16x2*>(Z + (size_t)s0 * D + lane * 2);
        ax += (float)v0[0];
        ay += (float)v0[1];
    }
    float r = 1.0f / fmaxf((float)deg, 1.0f);
    ax *= r; ay *= r;
    if (outH) {
        f16x2 o; o[0] = (_Float16)ax; o[1] = (_Float16)ay;
        *reinterpret_cast<f16x2*>(outH + (size_t)row * D + lane * 2) = o;
    } else {
        *reinterpret_cast<float2*>(outF + (size_t)row * D + lane * 2) =
            make_float2(ax, ay);
    }
}

// ---------------------------------------------------------------------------
// Zrev/Zll = x_label @ {W_l_tl, W_l_ll}^T, fp16, permuted layout.
// Swapped mfma(W, x): lane (q,m15) owns x-row base+m15, cols nt*16+q*4+{0..3}.
// ---------------------------------------------------------------------------
__global__ __launch_bounds__(256) void z_label_gemm(
    const float* __restrict__ labelEmbed, const int* __restrict__ labelNodeId,
    const __bf16* __restrict__ Wb,
    _Float16* __restrict__ Zrev, _Float16* __restrict__ Zll)
{
    const int w = threadIdx.x >> 6;
    const int lane = threadIdx.x & 63;
    const int m15 = lane & 15, q = lane >> 4;
    const int rowOrig = blockIdx.x * 64 + w * 16 + m15;
    const int row = (rowOrig < NL) ? rowOrig : NL - 1;
    const int xr = labelNodeId[row];

    bf16x8 aE[4];
    const float* pe = labelEmbed + (size_t)xr * D + q * 8;
#pragma unroll
    for (int kc = 0; kc < 4; ++kc) {
        float4 f0 = *reinterpret_cast<const float4*>(pe + kc * 32);
        float4 f1 = *reinterpret_cast<const float4*>(pe + kc * 32 + 4);
        aE[kc] = cvt8(f0, f1);
    }

    const f32x4 z4 = {0.f, 0.f, 0.f, 0.f};
#pragma unroll
    for (int pass = 0; pass < 2; ++pass) {
        const __bf16* W = Wb + (pass ? 2 * D * D : 0);
        _Float16* Z = pass ? Zll : Zrev;
        f32x4 acc[8];
#pragma unroll
        for (int nt = 0; nt < 8; ++nt) acc[nt] = z4;
#pragma unroll
        for (int kc = 0; kc < 4; ++kc) {
#pragma unroll
            for (int nt = 0; nt < 8; ++nt) {
                bf16x8 wf = *reinterpret_cast<const bf16x8*>(
                    W + (nt * 16 + m15) * D + kc * 32 + q * 8);
                acc[nt] = __builtin_amdgcn_mfma_f32_16x16x32_bf16(wf, aE[kc], acc[nt], 0, 0, 0);
            }
        }
        if (rowOrig < NL) {
            f16x8* zp = reinterpret_cast<f16x8*>(Z + (size_t)row * D + q * 32);
#pragma unroll
            for (int k = 0; k < 4; ++k)
                zp[k] = pack8(acc[2 * k], acc[2 * k + 1]);
        }
    }
}

// ---------------------------------------------------------------------------
// Title side — pure streaming now:
//   Zta      = x_title @ W_l_tl^T                         (fp16, permuted)
//   outTitle = relu(x_title @ W_r_tl^T + b_tl + meanRev)  (fp32)
//   Zot      = f16 permuted shadow of outTitle            (optional)
// meanRev (fp32, permuted) ALIASES the outTitle region (row-disjoint across
// blocks; __syncthreads between all meanRev reads and any outTitle store).
// ---------------------------------------------------------------------------
__global__ __launch_bounds__(256) void gemm_title_mfma(
    const float* __restrict__ xTitle, const __bf16* __restrict__ Wb,
    const float* __restrict__ b_tl,
    _Float16* __restrict__ Zta, _Float16* __restrict__ Zot,
    float* outTitle /* also meanRev input — no restrict */)
{
    const int w = threadIdx.x >> 6;
    const int lane = threadIdx.x & 63;
    const int m15 = lane & 15, q = lane >> 4;
    const int row = blockIdx.x * 64 + w * 16 + m15;   // NT % 64 == 0

    bf16x8 aX[4];
    const float* px = xTitle + (size_t)row * D + q * 8;
#pragma unroll
    for (int kc = 0; kc < 4; ++kc) {
        float4 g0 = *reinterpret_cast<const float4*>(px + kc * 32);
        float4 g1 = *reinterpret_cast<const float4*>(px + kc * 32 + 4);
        aX[kc] = cvt8(g0, g1);
    }

    const f32x4 z4 = {0.f, 0.f, 0.f, 0.f};
    f32x4 acc[8];

    // Pass 1: W_l_tl -> Zta (fp16, permuted).
    const __bf16* W0 = Wb;
#pragma unroll
    for (int nt = 0; nt < 8; ++nt) acc[nt] = z4;
#pragma unroll
    for (int kc = 0; kc < 4; ++kc) {
#pragma unroll
        for (int nt = 0; nt < 8; ++nt) {
            bf16x8 wf = *reinterpret_cast<const bf16x8*>(
                W0 + (nt * 16 + m15) * D + kc * 32 + q * 8);
            acc[nt] = __builtin_amdgcn_mfma_f32_16x16x32_bf16(wf, aX[kc], acc[nt], 0, 0, 0);
        }
    }
    {
        f16x8* zp = reinterpret_cast<f16x8*>(Zta + (size_t)row * D + q * 32);
#pragma unroll
        for (int k = 0; k < 4; ++k)
            zp[k] = pack8(acc[2 * k], acc[2 * k + 1]);
    }

    // Pass 2: W_r_tl.
    const __bf16* W1 = Wb + D * D;
#pragma unroll
    for (int nt = 0; nt < 8; ++nt) acc[nt] = z4;
#pragma unroll
    for (int kc = 0; kc < 4; ++kc) {
#pragma unroll
        for (int nt = 0; nt < 8; ++nt) {
            bf16x8 wf = *reinterpret_cast<const bf16x8*>(
                W1 + (nt * 16 + m15) * D + kc * 32 + q * 8);
            acc[nt] = __builtin_amdgcn_mfma_f32_16x16x32_bf16(wf, aX[kc], acc[nt], 0, 0, 0);
        }
    }

    // Add precomputed rev mean (fp32 permuted, aliased in outTitle region).
    // Chunk c of the lane's 32 floats == acc[c] (nt = c).
    {
        const f32x4* mr = reinterpret_cast<const f32x4*>(
            outTitle + (size_t)row * D + q * 32);
#pragma unroll
        for (int c = 0; c < 8; ++c) {
            f32x4 mv = mr[c];
            acc[c][0] += mv[0]; acc[c][1] += mv[1];
            acc[c][2] += mv[2]; acc[c][3] += mv[3];
        }
    }
    __syncthreads();   // all meanRev reads complete before any outTitle store

    // bias + relu, store fp32 output (unpermuted) + f16 shadow (permuted).
#pragma unroll
    for (int nt = 0; nt < 8; ++nt) {
        float4 bb = *reinterpret_cast<const float4*>(b_tl + nt * 16 + q * 4);
        acc[nt][0] = fmaxf(acc[nt][0] + bb.x, 0.0f);
        acc[nt][1] = fmaxf(acc[nt][1] + bb.y, 0.0f);
        acc[nt][2] = fmaxf(acc[nt][2] + bb.z, 0.0f);
        acc[nt][3] = fmaxf(acc[nt][3] + bb.w, 0.0f);
        *reinterpret_cast<f32x4*>(outTitle + (size_t)row * D + nt * 16 + q * 4) = acc[nt];
    }
    if (Zot) {
        f16x8* zp = reinterpret_cast<f16x8*>(Zot + (size_t)row * D + q * 32);
#pragma unroll
        for (int k = 0; k < 4; ++k)
            zp[k] = pack8(acc[2 * k], acc[2 * k + 1]);
    }
}

// ---------------------------------------------------------------------------
// Label side — pure streaming:
//   outLabel = relu(meanTa + meanLl + x_label @ (Wr_tl+Wr_ll)^T + b_sum)
//   Zol      = f16 permuted shadow (for pred), overlays dead Zll.
// ---------------------------------------------------------------------------
__global__ __launch_bounds__(256) void gemm_label_mfma(
    const float* __restrict__ labelEmbed, const int* __restrict__ labelNodeId,
    const __bf16* __restrict__ Wb, const float* __restrict__ bias_sum,
    const _Float16* __restrict__ meanTa, const _Float16* __restrict__ meanLl,
    float* __restrict__ outLabel, _Float16* __restrict__ Zol)
{
    const int w = threadIdx.x >> 6;
    const int lane = threadIdx.x & 63;
    const int m15 = lane & 15, q = lane >> 4;
    const int rowOrig = blockIdx.x * 64 + w * 16 + m15;
    const int row = (rowOrig < NL) ? rowOrig : NL - 1;   // clamp (partial last block)
    const int xr = labelNodeId[row];

    bf16x8 aXl[4];
    const float* pe = labelEmbed + (size_t)xr * D + q * 8;
#pragma unroll
    for (int kc = 0; kc < 4; ++kc) {
        float4 h0 = *reinterpret_cast<const float4*>(pe + kc * 32);
        float4 h1 = *reinterpret_cast<const float4*>(pe + kc * 32 + 4);
        aXl[kc] = cvt8(h0, h1);
    }

    const f32x4 z4 = {0.f, 0.f, 0.f, 0.f};
    f32x4 acc[8];
#pragma unroll
    for (int nt = 0; nt < 8; ++nt) acc[nt] = z4;

    const __bf16* W3 = Wb + 3 * D * D;   // W_r_tl + W_r_ll
#pragma unroll
    for (int kc = 0; kc < 4; ++kc) {
#pragma unroll
        for (int nt = 0; nt < 8; ++nt) {
            bf16x8 wf = *reinterpret_cast<const bf16x8*>(
                W3 + (nt * 16 + m15) * D + kc * 32 + q * 8);
            acc[nt] = __builtin_amdgcn_mfma_f32_16x16x32_bf16(wf, aXl[kc], acc[nt], 0, 0, 0);
        }
    }

    // Add the two precomputed means (f16 permuted, contiguous per lane).
    {
        const f16x8* mt = reinterpret_cast<const f16x8*>(meanTa + (size_t)row * D + q * 32);
        const f16x8* ml = reinterpret_cast<const f16x8*>(meanLl + (size_t)row * D + q * 32);
#pragma unroll
        for (int k = 0; k < 4; ++k) {
            f16x8 a = mt[k];
            f16x8 b = ml[k];
#pragma unroll
            for (int h = 0; h < 8; ++h) {
                int j = k * 8 + h;          // = nt*4 + i
                acc[j >> 2][j & 3] += (float)a[h] + (float)b[h];
            }
        }
    }

    // bias + relu; store outLabel (unpermuted) + Zol shadow (permuted).
#pragma unroll
    for (int nt = 0; nt < 8; ++nt) {
        float4 bb = *reinterpret_cast<const float4*>(bias_sum + nt * 16 + q * 4);
        acc[nt][0] = fmaxf(acc[nt][0] + bb.x, 0.0f);
        acc[nt][1] = fmaxf(acc[nt][1] + bb.y, 0.0f);
        acc[nt][2] = fmaxf(acc[nt][2] + bb.z, 0.0f);
        acc[nt][3] = fmaxf(acc[nt][3] + bb.w, 0.0f);
    }
    if (rowOrig < NL) {
#pragma unroll
        for (int nt = 0; nt < 8; ++nt)
            *reinterpret_cast<f32x4*>(outLabel + (size_t)row * D + nt * 16 + q * 4) = acc[nt];
        f16x8* zp = reinterpret_cast<f16x8*>(Zol + (size_t)row * D + q * 32);
#pragma unroll
        for (int k = 0; k < 4; ++k)
            zp[k] = pack8(acc[2 * k], acc[2 * k + 1]);
    }
}

// ---------------------------------------------------------------------------
// Supervision-edge dot products, standalone (max TLP): 32 lanes/edge.
// Gathers f16 shadows (256 B/row each side). Both sides share the same
// permutation, so the dot is layout-invariant. If Zot is absent (ws too
// small), reads outTitle fp32 with the permutation unmapped.
// ---------------------------------------------------------------------------
__global__ __launch_bounds__(256) void pred_kernel(
    const _Float16* __restrict__ Zot, const float* __restrict__ outTitle,
    const _Float16* __restrict__ Zol,
    const int* __restrict__ elSrc, const int* __restrict__ elDst,
    float* __restrict__ pred, int E)
{
    int idx = blockIdx.x * 256 + threadIdx.x;
    int e = idx >> 5;
    if (e >= E) return;
    int l = idx & 31;
    int s = elSrc[e];
    int d = elDst[e];
    f16x4 b = *reinterpret_cast<const f16x4*>(Zol + (size_t)d * D + l * 4);
    float v;
    if (Zot) {
        f16x4 a = *reinterpret_cast<const f16x4*>(Zot + (size_t)s * D + l * 4);
        v = (float)a[0] * (float)b[0] + (float)a[1] * (float)b[1]
          + (float)a[2] * (float)b[2] + (float)a[3] * (float)b[3];
    } else {
        // permuted pos l*4+i  ->  logical (l&7)*16 + (l>>3)*4 + i
        const float* at = outTitle + (size_t)s * D + (l & 7) * 16 + (l >> 3) * 4;
        float4 a = *reinterpret_cast<const float4*>(at);
        v = a.x * (float)b[0] + a.y * (float)b[1]
          + a.z * (float)b[2] + a.w * (float)b[3];
    }
#pragma unroll
    for (int off = 16; off > 0; off >>= 1) v += __shfl_down(v, off, 32);
    if (l == 0) pred[e] = v;
}

// ---------------------------------------------------------------------------
extern "C" void kernel_launch(void* const* d_in, const int* in_sizes, int n_in,
                              void* d_out, int out_size, void* d_ws, size_t ws_size,
                              hipStream_t stream)
{
    const float* x_title       = (const float*)d_in[0];
    const float* label_embed   = (const float*)d_in[1];
    const float* W_l_tl        = (const float*)d_in[2];
    const float* b_l_tl        = (const float*)d_in[3];
    const float* W_r_tl        = (const float*)d_in[4];
    const float* W_l_ll        = (const float*)d_in[5];
    const float* b_l_ll        = (const float*)d_in[6];
    const float* W_r_ll        = (const float*)d_in[7];
    const int*   label_node_id = (const int*)d_in[8];
    const int*   ta_src        = (const int*)d_in[9];
    const int*   ta_dst        = (const int*)d_in[10];
    const int*   rev_src       = (const int*)d_in[11];
    const int*   rev_dst       = (const int*)d_in[12];
    const int*   ll_src        = (const int*)d_in[13];
    const int*   ll_dst        = (const int*)d_in[14];
    const int*   el_src        = (const int*)d_in[15];
    const int*   el_dst        = (const int*)d_in[16];

    float* out       = (float*)d_out;
    float* pred      = out;                        // [ELBL]
    float* out_title = out + ELBL;                 // [NT*D] — hosts meanRev first
    float* out_label = out_title + (size_t)NT * D; // [NL*D]

    // Workspace layout (~101.5 MB mandatory, +51.2 MB optional Zot).
    char* p = (char*)d_ws;
    __bf16*   Wb      = (__bf16*)p;            p += (size_t)4 * D * D * sizeof(__bf16);
    float*    bias_sum= (float*)p;             p += D * sizeof(float);
    _Float16* Zta     = (_Float16*)p;          p += (size_t)NT * D * sizeof(_Float16);
    _Float16* Zrev    = Zta;                   // Zrev dies before Zta is born
    _Float16* Zll     = (_Float16*)p;          p += (size_t)NL * D * sizeof(_Float16);
    _Float16* Zol     = Zll;                   // Zol overlays dead Zll
    _Float16* meanTa  = (_Float16*)p;          p += (size_t)NL * D * sizeof(_Float16);
    _Float16* meanLl  = (_Float16*)p;          p += (size_t)NL * D * sizeof(_Float16);
    int*      cntTa   = (int*)p;               p += NL * sizeof(int);
    int*      cntLl   = (int*)p;               p += NL * sizeof(int);
    int*      cntRev  = (int*)p;               p += NT * sizeof(int);
    int*      gcnt    = (int*)p;               p += 4 * sizeof(int);
    int*      curTa   = (int*)p;               p += NL * sizeof(int);
    int*      curLl   = (int*)p;               p += NL * sizeof(int);
    int*      curRev  = (int*)p;               p += NT * sizeof(int);
    int*      csrTa   = (int*)p;               p += ETA * sizeof(int);
    int*      csrLl   = (int*)p;               p += ELL * sizeof(int);
    int*      csrRev  = (int*)p;               p += EREV * sizeof(int);
    _Float16* Zot     = (_Float16*)p;          p += (size_t)NT * D * sizeof(_Float16);
    if ((size_t)(p - (char*)d_ws) > ws_size) Zot = nullptr;   // pred falls back

    // Zero degree counters + the global cursors (contiguous).
    hipMemsetAsync(cntTa, 0, (size_t)(NL + NL + NT + 4) * sizeof(int), stream);

    prep_weights<<<(D * D + 255) / 256, 256, 0, stream>>>(
        W_l_tl, W_r_tl, W_l_ll, W_r_ll, b_l_tl, b_l_ll, Wb, bias_sum);

    // Z tables (label rows through W_l_tl / W_l_ll), fp16 permuted layout.
    z_label_gemm<<<(NL + 63) / 64, 256, 0, stream>>>(
        label_embed, label_node_id, Wb, Zrev, Zll);

    // Degree histograms.
    count_kernel<<<(ETA  + 255) / 256, 256, 0, stream>>>(ta_dst,  cntTa,  ETA);
    count_kernel<<<(ELL  + 255) / 256, 256, 0, stream>>>(ll_dst,  cntLl,  ELL);
    count_kernel<<<(EREV + 255) / 256, 256, 0, stream>>>(rev_dst, cntRev, EREV);

    // Segment allocation (order-free, one atomic per wave).
    alloc_kernel<<<(NL + 255) / 256, 256, 0, stream>>>(cntTa,  curTa,  gcnt + 0, NL);
    alloc_kernel<<<(NL + 255) / 256, 256, 0, stream>>>(cntLl,  curLl,  gcnt + 1, NL);
    alloc_kernel<<<(NT + 255) / 256, 256, 0, stream>>>(cntRev, curRev, gcnt + 2, NT);

    // CSR fills (store raw source row ids — Z tables are in source row space).
    fill_kernel<<<(ETA  + 255) / 256, 256, 0, stream>>>(ta_src,  ta_dst,  curTa,  csrTa,  ETA);
    fill_kernel<<<(ELL  + 255) / 256, 256, 0, stream>>>(ll_src,  ll_dst,  curLl,  csrLl,  ELL);
    fill_kernel<<<(EREV + 255) / 256, 256, 0, stream>>>(rev_src, rev_dst, curRev, csrRev, EREV);

    // rev mean: Zrev -> fp32 permuted, written into the outTitle region.
    agg_zmean<<<NT / 4, 256, 0, stream>>>(
        Zrev, csrRev, cntRev, curRev, nullptr, out_title, NT);

    // Title GEMM (streams meanRev from its own output region; writes Zta,
    // outTitle, optional Zot). Clobbers Zrev (dead).
    gemm_title_mfma<<<NT / 64, 256, 0, stream>>>(
        x_title, Wb, b_l_tl, Zta, Zot, out_title);

    // ta / ll means (f16 out).
    agg_zmean<<<(NL + 3) / 4, 256, 0, stream>>>(
        Zta, csrTa, cntTa, curTa, meanTa, nullptr, NL);
    agg_zmean<<<(NL + 3) / 4, 256, 0, stream>>>(
        Zll, csrLl, cntLl, curLl, meanLl, nullptr, NL);

    // Label GEMM (pure streaming; writes outLabel + Zol over dead Zll).
    gemm_label_mfma<<<(NL + 63) / 64, 256, 0, stream>>>(
        label_embed, label_node_id, Wb, bias_sum, meanTa, meanLl,
        out_label, Zol);

    // Supervision-edge dot products (f16 shadows both sides if Zot fits).
    pred_kernel<<<(ELBL * 32) / 256, 256, 0, stream>>>(
        Zot, out_title, Zol, el_src, el_dst, pred, ELBL);
}

// Round 6
// 900.042 us; speedup vs baseline: 1.1038x; 1.1038x over previous
//
#include <hip/hip_runtime.h>

#define D     128
#define NT    200000
#define NL    50000
#define ETA   1000000
#define EREV  1000000
#define ELL   500000
#define ELBL  500000
#define DD    (D * D)

typedef __attribute__((ext_vector_type(8))) __bf16 bf16x8;
typedef __attribute__((ext_vector_type(4))) float f32x4;
typedef __attribute__((ext_vector_type(2))) _Float16 f16x2;
typedef __attribute__((ext_vector_type(4))) _Float16 f16x4;
typedef __attribute__((ext_vector_type(8))) _Float16 f16x8;

__device__ inline bf16x8 cvt8(float4 a, float4 b)
{
    bf16x8 r;
    r[0] = (__bf16)a.x; r[1] = (__bf16)a.y; r[2] = (__bf16)a.z; r[3] = (__bf16)a.w;
    r[4] = (__bf16)b.x; r[5] = (__bf16)b.y; r[6] = (__bf16)b.z; r[7] = (__bf16)b.w;
    return r;
}

__device__ inline f16x8 pack8(const f32x4& a, const f32x4& b)
{
    f16x8 o;
    o[0] = (_Float16)a[0]; o[1] = (_Float16)a[1];
    o[2] = (_Float16)a[2]; o[3] = (_Float16)a[3];
    o[4] = (_Float16)b[0]; o[5] = (_Float16)b[1];
    o[6] = (_Float16)b[2]; o[7] = (_Float16)b[3];
    return o;
}

// ---------------------------------------------------------------------------
// Z/mean tables: PERMUTED per-row layout matching the MFMA C-fragment:
//   perm[row][q*32 + nt*4 + i] == logical[row][nt*16 + q*4 + i]
// Weights: FRAGMENT-ORDERED bf16 — frag f=(kc*8+nt) occupies 64 bf16x8 units
// at [f*64 + lane], lane=(q*16+m15), holding W[nt*16+m15][kc*32+q*8 .. +7].
// LDS staging is a linear copy; ds_read_b128 of a frag is 64 lanes x 16 B
// contiguous = conflict-free.
// ---------------------------------------------------------------------------

__global__ __launch_bounds__(256) void prep_weights(
    const float* __restrict__ Wl_tl, const float* __restrict__ Wr_tl,
    const float* __restrict__ Wl_ll, const float* __restrict__ Wr_ll,
    const float* __restrict__ b_tl, const float* __restrict__ b_ll,
    __bf16* __restrict__ Wb, float* __restrict__ bias_sum)
{
    int i = blockIdx.x * 256 + threadIdx.x;
    if (i < DD) {
        int n = i >> 7, k = i & 127;
        int kc = k >> 5, q = (k >> 3) & 3, j = k & 7;
        int nt = n >> 4, m15 = n & 15;
        int dst = (((kc * 8 + nt) * 4 + q) * 16 + m15) * 8 + j;
        Wb[dst]          = (__bf16)Wl_tl[i];   // slot 0: W_l_tl
        Wb[DD + dst]     = (__bf16)Wr_tl[i];   // slot 1: W_r_tl
        Wb[2 * DD + dst] = (__bf16)Wl_ll[i];   // slot 2: W_l_ll
        Wb[3 * DD + dst] = (__bf16)(Wr_tl[i] + Wr_ll[i]); // slot 3: sum
    }
    if (i < D) bias_sum[i] = b_tl[i] + b_ll[i];
}

// ---------------------------------------------------------------------------
// Fused degree count over all three relations.
// ---------------------------------------------------------------------------
__global__ __launch_bounds__(256) void count3_kernel(
    const int* __restrict__ taD, const int* __restrict__ llD,
    const int* __restrict__ revD,
    int* __restrict__ cntTa, int* __restrict__ cntLl, int* __restrict__ cntRev)
{
    int i = blockIdx.x * 256 + threadIdx.x;
    if (i < ETA) { atomicAdd(&cntTa[taD[i]], 1); return; }
    i -= ETA;
    if (i < ELL) { atomicAdd(&cntLl[llD[i]], 1); return; }
    i -= ELL;
    if (i < EREV) atomicAdd(&cntRev[revD[i]], 1);
}

// ---------------------------------------------------------------------------
// Fused segment allocation: block-granular relation split (waves never
// straddle), wave prefix-sum + one atomicAdd per wave.
// ---------------------------------------------------------------------------
#define BA ((NL + 255) / 256)   // 196 blocks per NL relation
#define BC ((NT + 255) / 256)   // 782 blocks for rev
__global__ __launch_bounds__(256) void alloc3_kernel(
    const int* __restrict__ cntTa, int* __restrict__ curTa,
    const int* __restrict__ cntLl, int* __restrict__ curLl,
    const int* __restrict__ cntRev, int* __restrict__ curRev,
    int* __restrict__ gcnt)
{
    int b = blockIdx.x;
    const int* cnt; int* cur; int* g; int n; int local;
    if (b < BA)            { cnt = cntTa;  cur = curTa;  g = gcnt + 0; n = NL; local = b * 256 + threadIdx.x; }
    else if (b < 2 * BA)   { cnt = cntLl;  cur = curLl;  g = gcnt + 1; n = NL; local = (b - BA) * 256 + threadIdx.x; }
    else                   { cnt = cntRev; cur = curRev; g = gcnt + 2; n = NT; local = (b - 2 * BA) * 256 + threadIdx.x; }
    int lane = threadIdx.x & 63;
    int deg = (local < n) ? cnt[local] : 0;
    int incl = deg;
#pragma unroll
    for (int off = 1; off < 64; off <<= 1) {
        int v = __shfl_up(incl, off, 64);
        if (lane >= off) incl += v;
    }
    int excl = incl - deg;
    int total = __shfl(incl, 63, 64);
    int base = 0;
    if (lane == 63) base = atomicAdd(g, total);
    base = __shfl(base, 63, 64);
    if (local < n) cur[local] = base + excl;
}

// ---------------------------------------------------------------------------
// Fused CSR fill. After this, cur[row] == segment end.
// ---------------------------------------------------------------------------
__global__ __launch_bounds__(256) void fill3_kernel(
    const int* __restrict__ taS, const int* __restrict__ taD,
    int* __restrict__ curTa, int* __restrict__ csrTa,
    const int* __restrict__ llS, const int* __restrict__ llD,
    int* __restrict__ curLl, int* __restrict__ csrLl,
    const int* __restrict__ revS, const int* __restrict__ revD,
    int* __restrict__ curRev, int* __restrict__ csrRev)
{
    int i = blockIdx.x * 256 + threadIdx.x;
    if (i < ETA) { int p = atomicAdd(&curTa[taD[i]], 1); csrTa[p] = taS[i]; return; }
    i -= ETA;
    if (i < ELL) { int p = atomicAdd(&curLl[llD[i]], 1); csrLl[p] = llS[i]; return; }
    i -= ELL;
    if (i < EREV) { int p = atomicAdd(&curRev[revD[i]], 1); csrRev[p] = revS[i]; }
}

// ---------------------------------------------------------------------------
// rev mean: Zrev (f16 permuted) -> fp32 permuted, into the outTitle region.
// One wave per dst row, one fully-coalesced 256 B load per edge.
// ---------------------------------------------------------------------------
__global__ __launch_bounds__(256) void agg_rev_kernel(
    const _Float16* __restrict__ Z, const int* __restrict__ csr,
    const int* __restrict__ cnt, const int* __restrict__ cur,
    float* __restrict__ outF)
{
    int row = blockIdx.x * 4 + (threadIdx.x >> 6);
    if (row >= NT) return;
    int lane = threadIdx.x & 63;
    int deg = cnt[row];
    int end = cur[row];
    int e = end - deg;
    float ax = 0.f, ay = 0.f;
    for (; e + 3 < end; e += 4) {
        int s0 = csr[e], s1 = csr[e + 1], s2 = csr[e + 2], s3 = csr[e + 3];
        f16x2 v0 = *reinterpret_cast<const f16x2*>(Z + (size_t)s0 * D + lane * 2);
        f16x2 v1 = *reinterpret_cast<const f16x2*>(Z + (size_t)s1 * D + lane * 2);
        f16x2 v2 = *reinterpret_cast<const f16x2*>(Z + (size_t)s2 * D + lane * 2);
        f16x2 v3 = *reinterpret_cast<const f16x2*>(Z + (size_t)s3 * D + lane * 2);
        ax += (float)v0[0] + (float)v1[0] + (float)v2[0] + (float)v3[0];
        ay += (float)v0[1] + (float)v1[1] + (float)v2[1] + (float)v3[1];
    }
    for (; e < end; ++e) {
        int s0 = csr[e];
        f16x2 v0 = *reinterpret_cast<const f16x2*>(Z + (size_t)s0 * D + lane * 2);
        ax += (float)v0[0];
        ay += (float)v0[1];
    }
    float r = 1.0f / fmaxf((float)deg, 1.0f);
    *reinterpret_cast<float2*>(outF + (size_t)row * D + lane * 2) =
        make_float2(ax * r, ay * r);
}

// ---------------------------------------------------------------------------
// Fused ta + ll means (f16 out), block-granular split.
// ---------------------------------------------------------------------------
#define BTA ((NL + 3) / 4)   // 12500 blocks per relation
__global__ __launch_bounds__(256) void agg_ta_ll_kernel(
    const _Float16* __restrict__ Zta, const int* __restrict__ csrTa,
    const int* __restrict__ cntTa, const int* __restrict__ curTa,
    _Float16* __restrict__ meanTa,
    const _Float16* __restrict__ Zll, const int* __restrict__ csrLl,
    const int* __restrict__ cntLl, const int* __restrict__ curLl,
    _Float16* __restrict__ meanLl)
{
    int b = blockIdx.x;
    const _Float16* Z; const int *csr, *cnt, *cur; _Float16* o;
    if (b < BTA) { Z = Zta; csr = csrTa; cnt = cntTa; cur = curTa; o = meanTa; }
    else { b -= BTA; Z = Zll; csr = csrLl; cnt = cntLl; cur = curLl; o = meanLl; }
    int row = b * 4 + (threadIdx.x >> 6);
    if (row >= NL) return;
    int lane = threadIdx.x & 63;
    int deg = cnt[row];
    int end = cur[row];
    int e = end - deg;
    float ax = 0.f, ay = 0.f;
    for (; e + 3 < end; e += 4) {
        int s0 = csr[e], s1 = csr[e + 1], s2 = csr[e + 2], s3 = csr[e + 3];
        f16x2 v0 = *reinterpret_cast<const f16x2*>(Z + (size_t)s0 * D + lane * 2);
        f16x2 v1 = *reinterpret_cast<const f16x2*>(Z + (size_t)s1 * D + lane * 2);
        f16x2 v2 = *reinterpret_cast<const f16x2*>(Z + (size_t)s2 * D + lane * 2);
        f16x2 v3 = *reinterpret_cast<const f16x2*>(Z + (size_t)s3 * D + lane * 2);
        ax += (float)v0[0] + (float)v1[0] + (float)v2[0] + (float)v3[0];
        ay += (float)v0[1] + (float)v1[1] + (float)v2[1] + (float)v3[1];
    }
    for (; e < end; ++e) {
        int s0 = csr[e];
        f16x2 v0 = *reinterpret_cast<const f16x2*>(Z + (size_t)s0 * D + lane * 2);
        ax += (float)v0[0];
        ay += (float)v0[1];
    }
    float r = 1.0f / fmaxf((float)deg, 1.0f);
    f16x2 ov; ov[0] = (_Float16)(ax * r); ov[1] = (_Float16)(ay * r);
    *reinterpret_cast<f16x2*>(o + (size_t)row * D + lane * 2) = ov;
}

// ---------------------------------------------------------------------------
// Zrev/Zll = x_label @ {W_l_tl, W_l_ll}^T, fp16 permuted. W0+W2 in LDS.
// ---------------------------------------------------------------------------
__global__ __launch_bounds__(256) void z_label_gemm(
    const float* __restrict__ labelEmbed, const int* __restrict__ labelNodeId,
    const __bf16* __restrict__ Wb,
    _Float16* __restrict__ Zrev, _Float16* __restrict__ Zll)
{
    __shared__ __bf16 sW[2 * DD];   // 64 KiB: W0 | W2
    const int tid = threadIdx.x;
    const int lane = tid & 63;
    const int m15 = lane & 15, q = lane >> 4;
    const int rowOrig = blockIdx.x * 64 + (tid >> 6) * 16 + m15;
    const int row = (rowOrig < NL) ? rowOrig : NL - 1;
    const int xr = labelNodeId[row];

    // Issue x loads, then stage weights (x latency hides under staging).
    const float* pe = labelEmbed + (size_t)xr * D + q * 8;
    float4 xf[8];
#pragma unroll
    for (int kc = 0; kc < 4; ++kc) {
        xf[2 * kc]     = *reinterpret_cast<const float4*>(pe + kc * 32);
        xf[2 * kc + 1] = *reinterpret_cast<const float4*>(pe + kc * 32 + 4);
    }
    {
        const float4* g0 = reinterpret_cast<const float4*>(Wb);            // W0
        const float4* g2 = reinterpret_cast<const float4*>(Wb + 2 * DD);   // W2
        float4* ls = reinterpret_cast<float4*>(sW);
        for (int it = tid; it < 2048; it += 256) {
            ls[it] = g0[it];
            ls[2048 + it] = g2[it];
        }
    }
    bf16x8 aE[4];
#pragma unroll
    for (int kc = 0; kc < 4; ++kc) aE[kc] = cvt8(xf[2 * kc], xf[2 * kc + 1]);
    __syncthreads();

    const bf16x8* wl = reinterpret_cast<const bf16x8*>(sW);
    const f32x4 z4 = {0.f, 0.f, 0.f, 0.f};
#pragma unroll
    for (int pass = 0; pass < 2; ++pass) {
        const int sb = pass ? 2048 : 0;
        _Float16* Z = pass ? Zll : Zrev;
        f32x4 acc[8];
#pragma unroll
        for (int nt = 0; nt < 8; ++nt) acc[nt] = z4;
#pragma unroll
        for (int kc = 0; kc < 4; ++kc)
#pragma unroll
            for (int nt = 0; nt < 8; ++nt)
                acc[nt] = __builtin_amdgcn_mfma_f32_16x16x32_bf16(
                    wl[sb + (kc * 8 + nt) * 64 + lane], aE[kc], acc[nt], 0, 0, 0);
        if (rowOrig < NL) {
            f16x8* zp = reinterpret_cast<f16x8*>(Z + (size_t)row * D + q * 32);
#pragma unroll
            for (int k = 0; k < 4; ++k)
                zp[k] = pack8(acc[2 * k], acc[2 * k + 1]);
        }
    }
}

// ---------------------------------------------------------------------------
// Title side (W0+W1 in LDS):
//   Zta      = x_title @ W_l_tl^T                         (fp16, permuted)
//   outTitle = relu(x_title @ W_r_tl^T + b_tl + meanRev)  (fp32)
//   Zot      = f16 permuted shadow of outTitle            (optional)
// meanRev (fp32 permuted) aliases the outTitle region. Safe without barrier:
// each wave reads/writes only its own 16 rows, and the mr data is consumed
// (waitcnt) before any store issues in program order.
// ---------------------------------------------------------------------------
__global__ __launch_bounds__(256) void gemm_title_mfma(
    const float* __restrict__ xTitle, const __bf16* __restrict__ Wb,
    const float* __restrict__ b_tl,
    _Float16* __restrict__ Zta, _Float16* __restrict__ Zot,
    float* outTitle /* also meanRev input — no restrict */)
{
    __shared__ __bf16 sW[2 * DD];   // 64 KiB: W0 | W1
    const int tid = threadIdx.x;
    const int lane = tid & 63;
    const int m15 = lane & 15, q = lane >> 4;
    const int row = blockIdx.x * 64 + (tid >> 6) * 16 + m15;   // NT % 64 == 0

    const float* px = xTitle + (size_t)row * D + q * 8;
    float4 xf[8];
#pragma unroll
    for (int kc = 0; kc < 4; ++kc) {
        xf[2 * kc]     = *reinterpret_cast<const float4*>(px + kc * 32);
        xf[2 * kc + 1] = *reinterpret_cast<const float4*>(px + kc * 32 + 4);
    }
    {
        const float4* gs = reinterpret_cast<const float4*>(Wb);  // W0|W1 contiguous
        float4* ls = reinterpret_cast<float4*>(sW);
        for (int it = tid; it < 4096; it += 256) ls[it] = gs[it];
    }
    bf16x8 aX[4];
#pragma unroll
    for (int kc = 0; kc < 4; ++kc) aX[kc] = cvt8(xf[2 * kc], xf[2 * kc + 1]);

    // Prefetch meanRev (fp32 permuted, aliased in outTitle region).
    f32x4 mr[8];
    {
        const f32x4* mp = reinterpret_cast<const f32x4*>(outTitle + (size_t)row * D + q * 32);
#pragma unroll
        for (int c = 0; c < 8; ++c) mr[c] = mp[c];
    }
    __syncthreads();

    const bf16x8* wl = reinterpret_cast<const bf16x8*>(sW);
    const f32x4 z4 = {0.f, 0.f, 0.f, 0.f};
    f32x4 acc[8];

    // Pass 1: W0 -> Zta.
#pragma unroll
    for (int nt = 0; nt < 8; ++nt) acc[nt] = z4;
#pragma unroll
    for (int kc = 0; kc < 4; ++kc)
#pragma unroll
        for (int nt = 0; nt < 8; ++nt)
            acc[nt] = __builtin_amdgcn_mfma_f32_16x16x32_bf16(
                wl[(kc * 8 + nt) * 64 + lane], aX[kc], acc[nt], 0, 0, 0);
    {
        f16x8* zp = reinterpret_cast<f16x8*>(Zta + (size_t)row * D + q * 32);
#pragma unroll
        for (int k = 0; k < 4; ++k)
            zp[k] = pack8(acc[2 * k], acc[2 * k + 1]);
    }

    // Pass 2: W1 + meanRev + bias + relu.
#pragma unroll
    for (int nt = 0; nt < 8; ++nt) acc[nt] = z4;
#pragma unroll
    for (int kc = 0; kc < 4; ++kc)
#pragma unroll
        for (int nt = 0; nt < 8; ++nt)
            acc[nt] = __builtin_amdgcn_mfma_f32_16x16x32_bf16(
                wl[2048 + (kc * 8 + nt) * 64 + lane], aX[kc], acc[nt], 0, 0, 0);
#pragma unroll
    for (int c = 0; c < 8; ++c) {
        acc[c][0] += mr[c][0]; acc[c][1] += mr[c][1];
        acc[c][2] += mr[c][2]; acc[c][3] += mr[c][3];
    }
#pragma unroll
    for (int nt = 0; nt < 8; ++nt) {
        float4 bb = *reinterpret_cast<const float4*>(b_tl + nt * 16 + q * 4);
        acc[nt][0] = fmaxf(acc[nt][0] + bb.x, 0.0f);
        acc[nt][1] = fmaxf(acc[nt][1] + bb.y, 0.0f);
        acc[nt][2] = fmaxf(acc[nt][2] + bb.z, 0.0f);
        acc[nt][3] = fmaxf(acc[nt][3] + bb.w, 0.0f);
        *reinterpret_cast<f32x4*>(outTitle + (size_t)row * D + nt * 16 + q * 4) = acc[nt];
    }
    if (Zot) {
        f16x8* zp = reinterpret_cast<f16x8*>(Zot + (size_t)row * D + q * 32);
#pragma unroll
        for (int k = 0; k < 4; ++k)
            zp[k] = pack8(acc[2 * k], acc[2 * k + 1]);
    }
}

// ---------------------------------------------------------------------------
// Label side (W3 in LDS):
//   outLabel = relu(meanTa + meanLl + x_label @ (Wr_tl+Wr_ll)^T + b_sum)
//   Zol      = f16 permuted shadow (for pred), overlays dead Zll.
// ---------------------------------------------------------------------------
__global__ __launch_bounds__(256) void gemm_label_mfma(
    const float* __restrict__ labelEmbed, const int* __restrict__ labelNodeId,
    const __bf16* __restrict__ Wb, const float* __restrict__ bias_sum,
    const _Float16* __restrict__ meanTa, const _Float16* __restrict__ meanLl,
    float* __restrict__ outLabel, _Float16* __restrict__ Zol)
{
    __shared__ __bf16 sW[DD];   // 32 KiB: W3
    const int tid = threadIdx.x;
    const int lane = tid & 63;
    const int m15 = lane & 15, q = lane >> 4;
    const int rowOrig = blockIdx.x * 64 + (tid >> 6) * 16 + m15;
    const int row = (rowOrig < NL) ? rowOrig : NL - 1;
    const int xr = labelNodeId[row];

    const float* pe = labelEmbed + (size_t)xr * D + q * 8;
    float4 xf[8];
#pragma unroll
    for (int kc = 0; kc < 4; ++kc) {
        xf[2 * kc]     = *reinterpret_cast<const float4*>(pe + kc * 32);
        xf[2 * kc + 1] = *reinterpret_cast<const float4*>(pe + kc * 32 + 4);
    }
    {
        const float4* g3 = reinterpret_cast<const float4*>(Wb + 3 * DD);
        float4* ls = reinterpret_cast<float4*>(sW);
        for (int it = tid; it < 2048; it += 256) ls[it] = g3[it];
    }
    bf16x8 aXl[4];
#pragma unroll
    for (int kc = 0; kc < 4; ++kc) aXl[kc] = cvt8(xf[2 * kc], xf[2 * kc + 1]);

    // Prefetch the two means (f16 permuted, contiguous per lane).
    f16x8 mt[4], ml[4];
    {
        const f16x8* pt = reinterpret_cast<const f16x8*>(meanTa + (size_t)row * D + q * 32);
        const f16x8* pl = reinterpret_cast<const f16x8*>(meanLl + (size_t)row * D + q * 32);
#pragma unroll
        for (int k = 0; k < 4; ++k) { mt[k] = pt[k]; ml[k] = pl[k]; }
    }
    __syncthreads();

    const bf16x8* wl = reinterpret_cast<const bf16x8*>(sW);
    const f32x4 z4 = {0.f, 0.f, 0.f, 0.f};
    f32x4 acc[8];
#pragma unroll
    for (int nt = 0; nt < 8; ++nt) acc[nt] = z4;
#pragma unroll
    for (int kc = 0; kc < 4; ++kc)
#pragma unroll
        for (int nt = 0; nt < 8; ++nt)
            acc[nt] = __builtin_amdgcn_mfma_f32_16x16x32_bf16(
                wl[(kc * 8 + nt) * 64 + lane], aXl[kc], acc[nt], 0, 0, 0);

#pragma unroll
    for (int k = 0; k < 4; ++k) {
#pragma unroll
        for (int h = 0; h < 8; ++h) {
            int j = k * 8 + h;          // = nt*4 + i
            acc[j >> 2][j & 3] += (float)mt[k][h] + (float)ml[k][h];
        }
    }
#pragma unroll
    for (int nt = 0; nt < 8; ++nt) {
        float4 bb = *reinterpret_cast<const float4*>(bias_sum + nt * 16 + q * 4);
        acc[nt][0] = fmaxf(acc[nt][0] + bb.x, 0.0f);
        acc[nt][1] = fmaxf(acc[nt][1] + bb.y, 0.0f);
        acc[nt][2] = fmaxf(acc[nt][2] + bb.z, 0.0f);
        acc[nt][3] = fmaxf(acc[nt][3] + bb.w, 0.0f);
    }
    if (rowOrig < NL) {
#pragma unroll
        for (int nt = 0; nt < 8; ++nt)
            *reinterpret_cast<f32x4*>(outLabel + (size_t)row * D + nt * 16 + q * 4) = acc[nt];
        f16x8* zp = reinterpret_cast<f16x8*>(Zol + (size_t)row * D + q * 32);
#pragma unroll
        for (int k = 0; k < 4; ++k)
            zp[k] = pack8(acc[2 * k], acc[2 * k + 1]);
    }
}

// ---------------------------------------------------------------------------
// Supervision-edge dot products: 32 lanes/edge, f16 shadows both sides.
// Both sides share the permutation -> dot is layout-invariant.
// ---------------------------------------------------------------------------
__global__ __launch_bounds__(256) void pred_kernel(
    const _Float16* __restrict__ Zot, const float* __restrict__ outTitle,
    const _Float16* __restrict__ Zol,
    const int* __restrict__ elSrc, const int* __restrict__ elDst,
    float* __restrict__ pred, int E)
{
    int idx = blockIdx.x * 256 + threadIdx.x;
    int e = idx >> 5;
    if (e >= E) return;
    int l = idx & 31;
    int s = elSrc[e];
    int d = elDst[e];
    f16x4 b = *reinterpret_cast<const f16x4*>(Zol + (size_t)d * D + l * 4);
    float v;
    if (Zot) {
        f16x4 a = *reinterpret_cast<const f16x4*>(Zot + (size_t)s * D + l * 4);
        v = (float)a[0] * (float)b[0] + (float)a[1] * (float)b[1]
          + (float)a[2] * (float)b[2] + (float)a[3] * (float)b[3];
    } else {
        // permuted pos l*4+i -> logical (l&7)*16 + (l>>3)*4 + i
        const float* at = outTitle + (size_t)s * D + (l & 7) * 16 + (l >> 3) * 4;
        float4 a = *reinterpret_cast<const float4*>(at);
        v = a.x * (float)b[0] + a.y * (float)b[1]
          + a.z * (float)b[2] + a.w * (float)b[3];
    }
#pragma unroll
    for (int off = 16; off > 0; off >>= 1) v += __shfl_down(v, off, 32);
    if (l == 0) pred[e] = v;
}

// ---------------------------------------------------------------------------
extern "C" void kernel_launch(void* const* d_in, const int* in_sizes, int n_in,
                              void* d_out, int out_size, void* d_ws, size_t ws_size,
                              hipStream_t stream)
{
    const float* x_title       = (const float*)d_in[0];
    const float* label_embed   = (const float*)d_in[1];
    const float* W_l_tl        = (const float*)d_in[2];
    const float* b_l_tl        = (const float*)d_in[3];
    const float* W_r_tl        = (const float*)d_in[4];
    const float* W_l_ll        = (const float*)d_in[5];
    const float* b_l_ll        = (const float*)d_in[6];
    const float* W_r_ll        = (const float*)d_in[7];
    const int*   label_node_id = (const int*)d_in[8];
    const int*   ta_src        = (const int*)d_in[9];
    const int*   ta_dst        = (const int*)d_in[10];
    const int*   rev_src       = (const int*)d_in[11];
    const int*   rev_dst       = (const int*)d_in[12];
    const int*   ll_src        = (const int*)d_in[13];
    const int*   ll_dst        = (const int*)d_in[14];
    const int*   el_src        = (const int*)d_in[15];
    const int*   el_dst        = (const int*)d_in[16];

    float* out       = (float*)d_out;
    float* pred      = out;                        // [ELBL]
    float* out_title = out + ELBL;                 // [NT*D] — hosts meanRev first
    float* out_label = out_title + (size_t)NT * D; // [NL*D]

    // Workspace layout (~103 MB mandatory, +51.2 MB optional Zot).
    char* p = (char*)d_ws;
    __bf16*   Wb      = (__bf16*)p;            p += (size_t)4 * DD * sizeof(__bf16);
    float*    bias_sum= (float*)p;             p += D * sizeof(float);
    _Float16* Zta     = (_Float16*)p;          p += (size_t)NT * D * sizeof(_Float16);
    _Float16* Zrev    = Zta;                   // Zrev dies before Zta is born
    _Float16* Zll     = (_Float16*)p;          p += (size_t)NL * D * sizeof(_Float16);
    _Float16* Zol     = Zll;                   // Zol overlays dead Zll
    _Float16* meanTa  = (_Float16*)p;          p += (size_t)NL * D * sizeof(_Float16);
    _Float16* meanLl  = (_Float16*)p;          p += (size_t)NL * D * sizeof(_Float16);
    int*      cntTa   = (int*)p;               p += NL * sizeof(int);
    int*      cntLl   = (int*)p;               p += NL * sizeof(int);
    int*      cntRev  = (int*)p;               p += NT * sizeof(int);
    int*      gcnt    = (int*)p;               p += 4 * sizeof(int);
    int*      curTa   = (int*)p;               p += NL * sizeof(int);
    int*      curLl   = (int*)p;               p += NL * sizeof(int);
    int*      curRev  = (int*)p;               p += NT * sizeof(int);
    int*      csrTa   = (int*)p;               p += ETA * sizeof(int);
    int*      csrLl   = (int*)p;               p += ELL * sizeof(int);
    int*      csrRev  = (int*)p;               p += EREV * sizeof(int);
    _Float16* Zot     = (_Float16*)p;          p += (size_t)NT * D * sizeof(_Float16);
    if ((size_t)(p - (char*)d_ws) > ws_size) Zot = nullptr;   // pred falls back

    // Zero degree counters + global cursors (contiguous).
    hipMemsetAsync(cntTa, 0, (size_t)(NL + NL + NT + 4) * sizeof(int), stream);

    prep_weights<<<(DD + 255) / 256, 256, 0, stream>>>(
        W_l_tl, W_r_tl, W_l_ll, W_r_ll, b_l_tl, b_l_ll, Wb, bias_sum);

    z_label_gemm<<<(NL + 63) / 64, 256, 0, stream>>>(
        label_embed, label_node_id, Wb, Zrev, Zll);

    count3_kernel<<<(ETA + ELL + EREV + 255) / 256, 256, 0, stream>>>(
        ta_dst, ll_dst, rev_dst, cntTa, cntLl, cntRev);

    alloc3_kernel<<<2 * BA + BC, 256, 0, stream>>>(
        cntTa, curTa, cntLl, curLl, cntRev, curRev, gcnt);

    fill3_kernel<<<(ETA + ELL + EREV + 255) / 256, 256, 0, stream>>>(
        ta_src, ta_dst, curTa, csrTa,
        ll_src, ll_dst, curLl, csrLl,
        rev_src, rev_dst, curRev, csrRev);

    // rev mean: Zrev -> fp32 permuted, written into the outTitle region.
    agg_rev_kernel<<<NT / 4, 256, 0, stream>>>(
        Zrev, csrRev, cntRev, curRev, out_title);

    // Title GEMM (LDS weights; streams meanRev; writes Zta/outTitle/Zot).
    gemm_title_mfma<<<NT / 64, 256, 0, stream>>>(
        x_title, Wb, b_l_tl, Zta, Zot, out_title);

    // ta + ll means (fused).
    agg_ta_ll_kernel<<<2 * BTA, 256, 0, stream>>>(
        Zta, csrTa, cntTa, curTa, meanTa,
        Zll, csrLl, cntLl, curLl, meanLl);

    // Label GEMM (LDS weights; writes outLabel + Zol over dead Zll).
    gemm_label_mfma<<<(NL + 63) / 64, 256, 0, stream>>>(
        label_embed, label_node_id, Wb, bias_sum, meanTa, meanLl,
        out_label, Zol);

    pred_kernel<<<(ELBL * 32) / 256, 256, 0, stream>>>(
        Zot, out_title, Zol, el_src, el_dst, pred, ELBL);
}

// Round 7
// 659.030 us; speedup vs baseline: 1.5075x; 1.3657x over previous
//
#include <hip/hip_runtime.h>

#define D     128
#define NT    200000
#define NL    50000
#define ETA   1000000
#define EREV  1000000
#define ELL   500000
#define ELBL  500000
#define DD    (D * D)

// Bucketed CSR build parameters.
#define NBK   256                    // buckets per relation
#define CH    8192                   // edges per chunk block
#define NCH_TA  ((ETA  + CH - 1) / CH)   // 123
#define NCH_LL  ((ELL  + CH - 1) / CH)   // 62
#define NCH_REV ((EREV + CH - 1) / CH)   // 123
#define R_TA  ((NL + NBK - 1) / NBK)     // 196 rows per bucket
#define R_LL  R_TA
#define R_REV ((NT + NBK - 1) / NBK)     // 782
#define RMAX  800

typedef __attribute__((ext_vector_type(8))) __bf16 bf16x8;
typedef __attribute__((ext_vector_type(4))) float f32x4;
typedef __attribute__((ext_vector_type(2))) _Float16 f16x2;
typedef __attribute__((ext_vector_type(4))) _Float16 f16x4;
typedef __attribute__((ext_vector_type(8))) _Float16 f16x8;

__device__ inline bf16x8 cvt8(float4 a, float4 b)
{
    bf16x8 r;
    r[0] = (__bf16)a.x; r[1] = (__bf16)a.y; r[2] = (__bf16)a.z; r[3] = (__bf16)a.w;
    r[4] = (__bf16)b.x; r[5] = (__bf16)b.y; r[6] = (__bf16)b.z; r[7] = (__bf16)b.w;
    return r;
}

__device__ inline f16x8 pack8(const f32x4& a, const f32x4& b)
{
    f16x8 o;
    o[0] = (_Float16)a[0]; o[1] = (_Float16)a[1];
    o[2] = (_Float16)a[2]; o[3] = (_Float16)a[3];
    o[4] = (_Float16)b[0]; o[5] = (_Float16)b[1];
    o[6] = (_Float16)b[2]; o[7] = (_Float16)b[3];
    return o;
}

// ---------------------------------------------------------------------------
// Z/mean tables: PERMUTED per-row layout matching the MFMA C-fragment:
//   perm[row][q*32 + nt*4 + i] == logical[row][nt*16 + q*4 + i]
// Weights: FRAGMENT-ORDERED bf16 (frag f=kc*8+nt at [f*64+lane]).
// ---------------------------------------------------------------------------

__global__ __launch_bounds__(256) void prep_weights(
    const float* __restrict__ Wl_tl, const float* __restrict__ Wr_tl,
    const float* __restrict__ Wl_ll, const float* __restrict__ Wr_ll,
    const float* __restrict__ b_tl, const float* __restrict__ b_ll,
    __bf16* __restrict__ Wb, float* __restrict__ bias_sum)
{
    int i = blockIdx.x * 256 + threadIdx.x;
    if (i < DD) {
        int n = i >> 7, k = i & 127;
        int kc = k >> 5, q = (k >> 3) & 3, j = k & 7;
        int nt = n >> 4, m15 = n & 15;
        int dst = (((kc * 8 + nt) * 4 + q) * 16 + m15) * 8 + j;
        Wb[dst]          = (__bf16)Wl_tl[i];
        Wb[DD + dst]     = (__bf16)Wr_tl[i];
        Wb[2 * DD + dst] = (__bf16)Wl_ll[i];
        Wb[3 * DD + dst] = (__bf16)(Wr_tl[i] + Wr_ll[i]);
    }
    if (i < D) bias_sum[i] = b_tl[i] + b_ll[i];
}

// ---------------------------------------------------------------------------
// Pass A1: per-chunk bucket histograms (LDS atomics only).
// Block = one chunk of one relation. M[chunk][256] written fully.
// ---------------------------------------------------------------------------
__global__ __launch_bounds__(256) void part_count(
    const int* __restrict__ taD, const int* __restrict__ llD,
    const int* __restrict__ revD,
    int* __restrict__ MTa, int* __restrict__ MLl, int* __restrict__ MRev)
{
    __shared__ int h[NBK];
    int bb = blockIdx.x, tid = threadIdx.x;
    const int* dst; int E, R, chunk; int* M;
    if (bb < NCH_TA) { dst = taD; E = ETA; R = R_TA; M = MTa; chunk = bb; }
    else if (bb < NCH_TA + NCH_LL) { dst = llD; E = ELL; R = R_LL; M = MLl; chunk = bb - NCH_TA; }
    else { dst = revD; E = EREV; R = R_REV; M = MRev; chunk = bb - NCH_TA - NCH_LL; }

    h[tid] = 0;
    __syncthreads();
    int eBeg = chunk * CH, eEnd = min(E, eBeg + CH);
    for (int e = eBeg + tid; e < eEnd; e += 256)
        atomicAdd(&h[dst[e] / R], 1);
    __syncthreads();
    M[chunk * NBK + tid] = h[tid];
}

// ---------------------------------------------------------------------------
// Pass A2: column scan of the chunk x bucket matrix (one block per relation).
// M[c][b] becomes exclusive offset of chunk c within bucket b;
// bucketStart[b] = exclusive prefix of bucket totals; bucketStart[256] = E.
// ---------------------------------------------------------------------------
__global__ __launch_bounds__(256) void part_scan(
    int* __restrict__ MTa, int* __restrict__ MLl, int* __restrict__ MRev,
    int* __restrict__ bsTa, int* __restrict__ bsLl, int* __restrict__ bsRev)
{
    int rel = blockIdx.x, tid = threadIdx.x;
    int* M; int nCh; int* bs;
    if (rel == 0) { M = MTa; nCh = NCH_TA; bs = bsTa; }
    else if (rel == 1) { M = MLl; nCh = NCH_LL; bs = bsLl; }
    else { M = MRev; nCh = NCH_REV; bs = bsRev; }

    int run = 0;
    for (int c = 0; c < nCh; ++c) {
        int v = M[c * NBK + tid];
        M[c * NBK + tid] = run;
        run += v;
    }
    // exclusive prefix of run across 256 threads
    int lane = tid & 63, w = tid >> 6;
    int incl = run;
#pragma unroll
    for (int off = 1; off < 64; off <<= 1) {
        int v = __shfl_up(incl, off, 64);
        if (lane >= off) incl += v;
    }
    __shared__ int ws[4];
    if (lane == 63) ws[w] = incl;
    __syncthreads();
    int base = 0;
    for (int j = 0; j < w; ++j) base += ws[j];
    int excl = base + incl - run;
    bs[tid] = excl;
    if (tid == 255) bs[NBK] = excl + run;   // == E
}

// ---------------------------------------------------------------------------
// Pass A3: scatter edges into bucketed (src,dst) pair lists. LDS cursors.
// ---------------------------------------------------------------------------
__global__ __launch_bounds__(256) void part_scatter(
    const int* __restrict__ taS, const int* __restrict__ taD,
    const int* __restrict__ llS, const int* __restrict__ llD,
    const int* __restrict__ revS, const int* __restrict__ revD,
    const int* __restrict__ MTa, const int* __restrict__ MLl,
    const int* __restrict__ MRev,
    const int* __restrict__ bsTa, const int* __restrict__ bsLl,
    const int* __restrict__ bsRev,
    int2* __restrict__ pTa, int2* __restrict__ pLl, int2* __restrict__ pRev)
{
    __shared__ int cur[NBK];
    int bb = blockIdx.x, tid = threadIdx.x;
    const int *src, *dst, *M, *bs; int E, R, chunk; int2* pr;
    if (bb < NCH_TA) {
        src = taS; dst = taD; M = MTa; bs = bsTa; pr = pTa;
        E = ETA; R = R_TA; chunk = bb;
    } else if (bb < NCH_TA + NCH_LL) {
        src = llS; dst = llD; M = MLl; bs = bsLl; pr = pLl;
        E = ELL; R = R_LL; chunk = bb - NCH_TA;
    } else {
        src = revS; dst = revD; M = MRev; bs = bsRev; pr = pRev;
        E = EREV; R = R_REV; chunk = bb - NCH_TA - NCH_LL;
    }
    cur[tid] = bs[tid] + M[chunk * NBK + tid];
    __syncthreads();
    int eBeg = chunk * CH, eEnd = min(E, eBeg + CH);
    for (int e = eBeg + tid; e < eEnd; e += 256) {
        int d = dst[e], s = src[e];
        int pos = atomicAdd(&cur[d / R], 1);
        pr[pos] = make_int2(s, d);
    }
}

// ---------------------------------------------------------------------------
// Pass B: per-bucket CSR build. One block per bucket; LDS row histogram +
// prefix + LDS-ticket scatter. Writes cnt[row], cur[row] (=segment end) and
// csr (dst-ordered). All traffic confined to the bucket's contiguous window.
// ---------------------------------------------------------------------------
__global__ __launch_bounds__(256) void csr_build(
    const int2* __restrict__ pTa, const int* __restrict__ bsTa,
    int* __restrict__ cntTa, int* __restrict__ curTa, int* __restrict__ csrTa,
    const int2* __restrict__ pLl, const int* __restrict__ bsLl,
    int* __restrict__ cntLl, int* __restrict__ curLl, int* __restrict__ csrLl,
    const int2* __restrict__ pRev, const int* __restrict__ bsRev,
    int* __restrict__ cntRev, int* __restrict__ curRev, int* __restrict__ csrRev)
{
    __shared__ int counts[RMAX];
    __shared__ int starts[RMAX];
    __shared__ int ws[4];
    int bb = blockIdx.x, tid = threadIdx.x;
    const int2* pr; const int* bs; int *cnt, *cur, *csr; int R, n;
    if (bb < NBK) {
        pr = pTa; bs = bsTa; cnt = cntTa; cur = curTa; csr = csrTa;
        R = R_TA; n = NL;
    } else if (bb < 2 * NBK) {
        bb -= NBK;
        pr = pLl; bs = bsLl; cnt = cntLl; cur = curLl; csr = csrLl;
        R = R_LL; n = NL;
    } else {
        bb -= 2 * NBK;
        pr = pRev; bs = bsRev; cnt = cntRev; cur = curRev; csr = csrRev;
        R = R_REV; n = NT;
    }
    const int rowBase = bb * R;
    const int eBeg = bs[bb], eEnd = bs[bb + 1];
    const int K = (R + 255) / 256;   // rows per thread (1 or 4)

    for (int k = 0; k < K; ++k) {
        int r = tid * K + k;
        if (r < R) counts[r] = 0;
    }
    __syncthreads();
    for (int e = eBeg + tid; e < eEnd; e += 256)
        atomicAdd(&counts[pr[e].y - rowBase], 1);
    __syncthreads();

    // Exclusive prefix over counts[0..R): thread owns rows [tid*K, tid*K+K).
    int local[4]; int sum = 0;
    for (int k = 0; k < K; ++k) {
        int r = tid * K + k;
        int v = (r < R) ? counts[r] : 0;
        local[k] = sum;
        sum += v;
    }
    int lane = tid & 63, w = tid >> 6;
    int incl = sum;
#pragma unroll
    for (int off = 1; off < 64; off <<= 1) {
        int v = __shfl_up(incl, off, 64);
        if (lane >= off) incl += v;
    }
    if (lane == 63) ws[w] = incl;
    __syncthreads();
    int wbase = 0;
    for (int j = 0; j < w; ++j) wbase += ws[j];
    int tbase = wbase + incl - sum;

    for (int k = 0; k < K; ++k) {
        int r = tid * K + k;
        if (r < R) {
            int v = counts[r];
            int excl = tbase + local[k];
            starts[r] = excl;
            int row = rowBase + r;
            if (row < n) {
                cnt[row] = v;
                cur[row] = eBeg + excl + v;   // segment end
            }
        }
    }
    __syncthreads();

    // Scatter src ids via LDS tickets (starts -> mutates toward end).
    for (int e = eBeg + tid; e < eEnd; e += 256) {
        int2 p = pr[e];
        int pos = eBeg + atomicAdd(&starts[p.y - rowBase], 1);
        csr[pos] = p.x;
    }
}

// ---------------------------------------------------------------------------
// rev mean: Zrev (f16 permuted) -> fp32 permuted, into the outTitle region.
// ---------------------------------------------------------------------------
__global__ __launch_bounds__(256) void agg_rev_kernel(
    const _Float16* __restrict__ Z, const int* __restrict__ csr,
    const int* __restrict__ cnt, const int* __restrict__ cur,
    float* __restrict__ outF)
{
    int row = blockIdx.x * 4 + (threadIdx.x >> 6);
    if (row >= NT) return;
    int lane = threadIdx.x & 63;
    int deg = cnt[row];
    int end = cur[row];
    int e = end - deg;
    float ax = 0.f, ay = 0.f;
    for (; e + 3 < end; e += 4) {
        int s0 = csr[e], s1 = csr[e + 1], s2 = csr[e + 2], s3 = csr[e + 3];
        f16x2 v0 = *reinterpret_cast<const f16x2*>(Z + (size_t)s0 * D + lane * 2);
        f16x2 v1 = *reinterpret_cast<const f16x2*>(Z + (size_t)s1 * D + lane * 2);
        f16x2 v2 = *reinterpret_cast<const f16x2*>(Z + (size_t)s2 * D + lane * 2);
        f16x2 v3 = *reinterpret_cast<const f16x2*>(Z + (size_t)s3 * D + lane * 2);
        ax += (float)v0[0] + (float)v1[0] + (float)v2[0] + (float)v3[0];
        ay += (float)v0[1] + (float)v1[1] + (float)v2[1] + (float)v3[1];
    }
    for (; e < end; ++e) {
        int s0 = csr[e];
        f16x2 v0 = *reinterpret_cast<const f16x2*>(Z + (size_t)s0 * D + lane * 2);
        ax += (float)v0[0];
        ay += (float)v0[1];
    }
    float r = 1.0f / fmaxf((float)deg, 1.0f);
    *reinterpret_cast<float2*>(outF + (size_t)row * D + lane * 2) =
        make_float2(ax * r, ay * r);
}

// ---------------------------------------------------------------------------
// Fused ta + ll means (f16 out), block-granular split.
// ---------------------------------------------------------------------------
#define BTA ((NL + 3) / 4)
__global__ __launch_bounds__(256) void agg_ta_ll_kernel(
    const _Float16* __restrict__ Zta, const int* __restrict__ csrTa,
    const int* __restrict__ cntTa, const int* __restrict__ curTa,
    _Float16* __restrict__ meanTa,
    const _Float16* __restrict__ Zll, const int* __restrict__ csrLl,
    const int* __restrict__ cntLl, const int* __restrict__ curLl,
    _Float16* __restrict__ meanLl)
{
    int b = blockIdx.x;
    const _Float16* Z; const int *csr, *cnt, *cur; _Float16* o;
    if (b < BTA) { Z = Zta; csr = csrTa; cnt = cntTa; cur = curTa; o = meanTa; }
    else { b -= BTA; Z = Zll; csr = csrLl; cnt = cntLl; cur = curLl; o = meanLl; }
    int row = b * 4 + (threadIdx.x >> 6);
    if (row >= NL) return;
    int lane = threadIdx.x & 63;
    int deg = cnt[row];
    int end = cur[row];
    int e = end - deg;
    float ax = 0.f, ay = 0.f;
    for (; e + 3 < end; e += 4) {
        int s0 = csr[e], s1 = csr[e + 1], s2 = csr[e + 2], s3 = csr[e + 3];
        f16x2 v0 = *reinterpret_cast<const f16x2*>(Z + (size_t)s0 * D + lane * 2);
        f16x2 v1 = *reinterpret_cast<const f16x2*>(Z + (size_t)s1 * D + lane * 2);
        f16x2 v2 = *reinterpret_cast<const f16x2*>(Z + (size_t)s2 * D + lane * 2);
        f16x2 v3 = *reinterpret_cast<const f16x2*>(Z + (size_t)s3 * D + lane * 2);
        ax += (float)v0[0] + (float)v1[0] + (float)v2[0] + (float)v3[0];
        ay += (float)v0[1] + (float)v1[1] + (float)v2[1] + (float)v3[1];
    }
    for (; e < end; ++e) {
        int s0 = csr[e];
        f16x2 v0 = *reinterpret_cast<const f16x2*>(Z + (size_t)s0 * D + lane * 2);
        ax += (float)v0[0];
        ay += (float)v0[1];
    }
    float r = 1.0f / fmaxf((float)deg, 1.0f);
    f16x2 ov; ov[0] = (_Float16)(ax * r); ov[1] = (_Float16)(ay * r);
    *reinterpret_cast<f16x2*>(o + (size_t)row * D + lane * 2) = ov;
}

// ---------------------------------------------------------------------------
// Zrev/Zll = x_label @ {W_l_tl, W_l_ll}^T, fp16 permuted. W0+W2 in LDS.
// ---------------------------------------------------------------------------
__global__ __launch_bounds__(256) void z_label_gemm(
    const float* __restrict__ labelEmbed, const int* __restrict__ labelNodeId,
    const __bf16* __restrict__ Wb,
    _Float16* __restrict__ Zrev, _Float16* __restrict__ Zll)
{
    __shared__ __bf16 sW[2 * DD];
    const int tid = threadIdx.x;
    const int lane = tid & 63;
    const int m15 = lane & 15, q = lane >> 4;
    const int rowOrig = blockIdx.x * 64 + (tid >> 6) * 16 + m15;
    const int row = (rowOrig < NL) ? rowOrig : NL - 1;
    const int xr = labelNodeId[row];

    const float* pe = labelEmbed + (size_t)xr * D + q * 8;
    float4 xf[8];
#pragma unroll
    for (int kc = 0; kc < 4; ++kc) {
        xf[2 * kc]     = *reinterpret_cast<const float4*>(pe + kc * 32);
        xf[2 * kc + 1] = *reinterpret_cast<const float4*>(pe + kc * 32 + 4);
    }
    {
        const float4* g0 = reinterpret_cast<const float4*>(Wb);
        const float4* g2 = reinterpret_cast<const float4*>(Wb + 2 * DD);
        float4* ls = reinterpret_cast<float4*>(sW);
        for (int it = tid; it < 2048; it += 256) {
            ls[it] = g0[it];
            ls[2048 + it] = g2[it];
        }
    }
    bf16x8 aE[4];
#pragma unroll
    for (int kc = 0; kc < 4; ++kc) aE[kc] = cvt8(xf[2 * kc], xf[2 * kc + 1]);
    __syncthreads();

    const bf16x8* wl = reinterpret_cast<const bf16x8*>(sW);
    const f32x4 z4 = {0.f, 0.f, 0.f, 0.f};
#pragma unroll
    for (int pass = 0; pass < 2; ++pass) {
        const int sb = pass ? 2048 : 0;
        _Float16* Z = pass ? Zll : Zrev;
        f32x4 acc[8];
#pragma unroll
        for (int nt = 0; nt < 8; ++nt) acc[nt] = z4;
#pragma unroll
        for (int kc = 0; kc < 4; ++kc)
#pragma unroll
            for (int nt = 0; nt < 8; ++nt)
                acc[nt] = __builtin_amdgcn_mfma_f32_16x16x32_bf16(
                    wl[sb + (kc * 8 + nt) * 64 + lane], aE[kc], acc[nt], 0, 0, 0);
        if (rowOrig < NL) {
            f16x8* zp = reinterpret_cast<f16x8*>(Z + (size_t)row * D + q * 32);
#pragma unroll
            for (int k = 0; k < 4; ++k)
                zp[k] = pack8(acc[2 * k], acc[2 * k + 1]);
        }
    }
}

// ---------------------------------------------------------------------------
// Title GEMM (W0+W1 in LDS): Zta + outTitle(+meanRev)+Zot.
// ---------------------------------------------------------------------------
__global__ __launch_bounds__(256) void gemm_title_mfma(
    const float* __restrict__ xTitle, const __bf16* __restrict__ Wb,
    const float* __restrict__ b_tl,
    _Float16* __restrict__ Zta, _Float16* __restrict__ Zot,
    float* outTitle /* also meanRev input — no restrict */)
{
    __shared__ __bf16 sW[2 * DD];
    const int tid = threadIdx.x;
    const int lane = tid & 63;
    const int m15 = lane & 15, q = lane >> 4;
    const int row = blockIdx.x * 64 + (tid >> 6) * 16 + m15;

    const float* px = xTitle + (size_t)row * D + q * 8;
    float4 xf[8];
#pragma unroll
    for (int kc = 0; kc < 4; ++kc) {
        xf[2 * kc]     = *reinterpret_cast<const float4*>(px + kc * 32);
        xf[2 * kc + 1] = *reinterpret_cast<const float4*>(px + kc * 32 + 4);
    }
    {
        const float4* gs = reinterpret_cast<const float4*>(Wb);
        float4* ls = reinterpret_cast<float4*>(sW);
        for (int it = tid; it < 4096; it += 256) ls[it] = gs[it];
    }
    bf16x8 aX[4];
#pragma unroll
    for (int kc = 0; kc < 4; ++kc) aX[kc] = cvt8(xf[2 * kc], xf[2 * kc + 1]);

    f32x4 mr[8];
    {
        const f32x4* mp = reinterpret_cast<const f32x4*>(outTitle + (size_t)row * D + q * 32);
#pragma unroll
        for (int c = 0; c < 8; ++c) mr[c] = mp[c];
    }
    __syncthreads();

    const bf16x8* wl = reinterpret_cast<const bf16x8*>(sW);
    const f32x4 z4 = {0.f, 0.f, 0.f, 0.f};
    f32x4 acc[8];

#pragma unroll
    for (int nt = 0; nt < 8; ++nt) acc[nt] = z4;
#pragma unroll
    for (int kc = 0; kc < 4; ++kc)
#pragma unroll
        for (int nt = 0; nt < 8; ++nt)
            acc[nt] = __builtin_amdgcn_mfma_f32_16x16x32_bf16(
                wl[(kc * 8 + nt) * 64 + lane], aX[kc], acc[nt], 0, 0, 0);
    {
        f16x8* zp = reinterpret_cast<f16x8*>(Zta + (size_t)row * D + q * 32);
#pragma unroll
        for (int k = 0; k < 4; ++k)
            zp[k] = pack8(acc[2 * k], acc[2 * k + 1]);
    }

#pragma unroll
    for (int nt = 0; nt < 8; ++nt) acc[nt] = z4;
#pragma unroll
    for (int kc = 0; kc < 4; ++kc)
#pragma unroll
        for (int nt = 0; nt < 8; ++nt)
            acc[nt] = __builtin_amdgcn_mfma_f32_16x16x32_bf16(
                wl[2048 + (kc * 8 + nt) * 64 + lane], aX[kc], acc[nt], 0, 0, 0);
#pragma unroll
    for (int c = 0; c < 8; ++c) {
        acc[c][0] += mr[c][0]; acc[c][1] += mr[c][1];
        acc[c][2] += mr[c][2]; acc[c][3] += mr[c][3];
    }
#pragma unroll
    for (int nt = 0; nt < 8; ++nt) {
        float4 bb = *reinterpret_cast<const float4*>(b_tl + nt * 16 + q * 4);
        acc[nt][0] = fmaxf(acc[nt][0] + bb.x, 0.0f);
        acc[nt][1] = fmaxf(acc[nt][1] + bb.y, 0.0f);
        acc[nt][2] = fmaxf(acc[nt][2] + bb.z, 0.0f);
        acc[nt][3] = fmaxf(acc[nt][3] + bb.w, 0.0f);
        *reinterpret_cast<f32x4*>(outTitle + (size_t)row * D + nt * 16 + q * 4) = acc[nt];
    }
    if (Zot) {
        f16x8* zp = reinterpret_cast<f16x8*>(Zot + (size_t)row * D + q * 32);
#pragma unroll
        for (int k = 0; k < 4; ++k)
            zp[k] = pack8(acc[2 * k], acc[2 * k + 1]);
    }
}

// ---------------------------------------------------------------------------
// Label GEMM (W3 in LDS): outLabel + Zol.
// ---------------------------------------------------------------------------
__global__ __launch_bounds__(256) void gemm_label_mfma(
    const float* __restrict__ labelEmbed, const int* __restrict__ labelNodeId,
    const __bf16* __restrict__ Wb, const float* __restrict__ bias_sum,
    const _Float16* __restrict__ meanTa, const _Float16* __restrict__ meanLl,
    float* __restrict__ outLabel, _Float16* __restrict__ Zol)
{
    __shared__ __bf16 sW[DD];
    const int tid = threadIdx.x;
    const int lane = tid & 63;
    const int m15 = lane & 15, q = lane >> 4;
    const int rowOrig = blockIdx.x * 64 + (tid >> 6) * 16 + m15;
    const int row = (rowOrig < NL) ? rowOrig : NL - 1;
    const int xr = labelNodeId[row];

    const float* pe = labelEmbed + (size_t)xr * D + q * 8;
    float4 xf[8];
#pragma unroll
    for (int kc = 0; kc < 4; ++kc) {
        xf[2 * kc]     = *reinterpret_cast<const float4*>(pe + kc * 32);
        xf[2 * kc + 1] = *reinterpret_cast<const float4*>(pe + kc * 32 + 4);
    }
    {
        const float4* g3 = reinterpret_cast<const float4*>(Wb + 3 * DD);
        float4* ls = reinterpret_cast<float4*>(sW);
        for (int it = tid; it < 2048; it += 256) ls[it] = g3[it];
    }
    bf16x8 aXl[4];
#pragma unroll
    for (int kc = 0; kc < 4; ++kc) aXl[kc] = cvt8(xf[2 * kc], xf[2 * kc + 1]);

    f16x8 mt[4], ml[4];
    {
        const f16x8* pt = reinterpret_cast<const f16x8*>(meanTa + (size_t)row * D + q * 32);
        const f16x8* pl = reinterpret_cast<const f16x8*>(meanLl + (size_t)row * D + q * 32);
#pragma unroll
        for (int k = 0; k < 4; ++k) { mt[k] = pt[k]; ml[k] = pl[k]; }
    }
    __syncthreads();

    const bf16x8* wl = reinterpret_cast<const bf16x8*>(sW);
    const f32x4 z4 = {0.f, 0.f, 0.f, 0.f};
    f32x4 acc[8];
#pragma unroll
    for (int nt = 0; nt < 8; ++nt) acc[nt] = z4;
#pragma unroll
    for (int kc = 0; kc < 4; ++kc)
#pragma unroll
        for (int nt = 0; nt < 8; ++nt)
            acc[nt] = __builtin_amdgcn_mfma_f32_16x16x32_bf16(
                wl[(kc * 8 + nt) * 64 + lane], aXl[kc], acc[nt], 0, 0, 0);

#pragma unroll
    for (int k = 0; k < 4; ++k) {
#pragma unroll
        for (int h = 0; h < 8; ++h) {
            int j = k * 8 + h;
            acc[j >> 2][j & 3] += (float)mt[k][h] + (float)ml[k][h];
        }
    }
#pragma unroll
    for (int nt = 0; nt < 8; ++nt) {
        float4 bb = *reinterpret_cast<const float4*>(bias_sum + nt * 16 + q * 4);
        acc[nt][0] = fmaxf(acc[nt][0] + bb.x, 0.0f);
        acc[nt][1] = fmaxf(acc[nt][1] + bb.y, 0.0f);
        acc[nt][2] = fmaxf(acc[nt][2] + bb.z, 0.0f);
        acc[nt][3] = fmaxf(acc[nt][3] + bb.w, 0.0f);
    }
    if (rowOrig < NL) {
#pragma unroll
        for (int nt = 0; nt < 8; ++nt)
            *reinterpret_cast<f32x4*>(outLabel + (size_t)row * D + nt * 16 + q * 4) = acc[nt];
        f16x8* zp = reinterpret_cast<f16x8*>(Zol + (size_t)row * D + q * 32);
#pragma unroll
        for (int k = 0; k < 4; ++k)
            zp[k] = pack8(acc[2 * k], acc[2 * k + 1]);
    }
}

// ---------------------------------------------------------------------------
// Supervision-edge dot products: 32 lanes/edge, f16 shadows both sides.
// ---------------------------------------------------------------------------
__global__ __launch_bounds__(256) void pred_kernel(
    const _Float16* __restrict__ Zot, const float* __restrict__ outTitle,
    const _Float16* __restrict__ Zol,
    const int* __restrict__ elSrc, const int* __restrict__ elDst,
    float* __restrict__ pred, int E)
{
    int idx = blockIdx.x * 256 + threadIdx.x;
    int e = idx >> 5;
    if (e >= E) return;
    int l = idx & 31;
    int s = elSrc[e];
    int d = elDst[e];
    f16x4 b = *reinterpret_cast<const f16x4*>(Zol + (size_t)d * D + l * 4);
    float v;
    if (Zot) {
        f16x4 a = *reinterpret_cast<const f16x4*>(Zot + (size_t)s * D + l * 4);
        v = (float)a[0] * (float)b[0] + (float)a[1] * (float)b[1]
          + (float)a[2] * (float)b[2] + (float)a[3] * (float)b[3];
    } else {
        const float* at = outTitle + (size_t)s * D + (l & 7) * 16 + (l >> 3) * 4;
        float4 a = *reinterpret_cast<const float4*>(at);
        v = a.x * (float)b[0] + a.y * (float)b[1]
          + a.z * (float)b[2] + a.w * (float)b[3];
    }
#pragma unroll
    for (int off = 16; off > 0; off >>= 1) v += __shfl_down(v, off, 32);
    if (l == 0) pred[e] = v;
}

// ---------------------------------------------------------------------------
extern "C" void kernel_launch(void* const* d_in, const int* in_sizes, int n_in,
                              void* d_out, int out_size, void* d_ws, size_t ws_size,
                              hipStream_t stream)
{
    const float* x_title       = (const float*)d_in[0];
    const float* label_embed   = (const float*)d_in[1];
    const float* W_l_tl        = (const float*)d_in[2];
    const float* b_l_tl        = (const float*)d_in[3];
    const float* W_r_tl        = (const float*)d_in[4];
    const float* W_l_ll        = (const float*)d_in[5];
    const float* b_l_ll        = (const float*)d_in[6];
    const float* W_r_ll        = (const float*)d_in[7];
    const int*   label_node_id = (const int*)d_in[8];
    const int*   ta_src        = (const int*)d_in[9];
    const int*   ta_dst        = (const int*)d_in[10];
    const int*   rev_src       = (const int*)d_in[11];
    const int*   rev_dst       = (const int*)d_in[12];
    const int*   ll_src        = (const int*)d_in[13];
    const int*   ll_dst        = (const int*)d_in[14];
    const int*   el_src        = (const int*)d_in[15];
    const int*   el_dst        = (const int*)d_in[16];

    float* out       = (float*)d_out;
    float* pred      = out;                        // [ELBL]
    float* out_title = out + ELBL;                 // [NT*D] — hosts meanRev first
    float* out_label = out_title + (size_t)NT * D; // [NL*D]

    // Workspace layout (~103 MB mandatory, +51.2 MB optional Zot).
    char* p = (char*)d_ws;
    __bf16*   Wb      = (__bf16*)p;            p += (size_t)4 * DD * sizeof(__bf16);
    float*    bias_sum= (float*)p;             p += D * sizeof(float);
    _Float16* Zta     = (_Float16*)p;          p += (size_t)NT * D * sizeof(_Float16);
    _Float16* Zrev    = Zta;                   // Zrev dies before Zta is born
    _Float16* Zll     = (_Float16*)p;          p += (size_t)NL * D * sizeof(_Float16);
    _Float16* Zol     = Zll;                   // Zol overlays dead Zll
    _Float16* meanTa  = (_Float16*)p;          p += (size_t)NL * D * sizeof(_Float16);
    _Float16* meanLl  = (_Float16*)p;          p += (size_t)NL * D * sizeof(_Float16);
    // pairs buffers overlay meanTa/meanLl (dead until agg_ta_ll, which runs
    // after csr_build): 20 MB <= 25.6 MB.
    int2*     pTa     = (int2*)meanTa;                       // ETA int2 = 8 MB
    int2*     pLl     = (int2*)(pTa + ETA);                  // ELL int2 = 4 MB
    int2*     pRev    = (int2*)(pLl + ELL);                  // EREV int2 = 8 MB
    int*      cntTa   = (int*)p;               p += NL * sizeof(int);
    int*      cntLl   = (int*)p;               p += NL * sizeof(int);
    int*      cntRev  = (int*)p;               p += NT * sizeof(int);
    int*      curTa   = (int*)p;               p += NL * sizeof(int);
    int*      curLl   = (int*)p;               p += NL * sizeof(int);
    int*      curRev  = (int*)p;               p += NT * sizeof(int);
    int*      csrTa   = (int*)p;               p += ETA * sizeof(int);
    int*      csrLl   = (int*)p;               p += ELL * sizeof(int);
    int*      csrRev  = (int*)p;               p += EREV * sizeof(int);
    int*      MTa     = (int*)p;               p += (size_t)NCH_TA * NBK * sizeof(int);
    int*      MLl     = (int*)p;               p += (size_t)NCH_LL * NBK * sizeof(int);
    int*      MRev    = (int*)p;               p += (size_t)NCH_REV * NBK * sizeof(int);
    int*      bsTa    = (int*)p;               p += (NBK + 1) * sizeof(int);
    int*      bsLl    = (int*)p;               p += (NBK + 1) * sizeof(int);
    int*      bsRev   = (int*)p;               p += (NBK + 1) * sizeof(int);
    _Float16* Zot     = (_Float16*)p;          p += (size_t)NT * D * sizeof(_Float16);
    if ((size_t)(p - (char*)d_ws) > ws_size) Zot = nullptr;   // pred falls back

    prep_weights<<<(DD + 255) / 256, 256, 0, stream>>>(
        W_l_tl, W_r_tl, W_l_ll, W_r_ll, b_l_tl, b_l_ll, Wb, bias_sum);

    z_label_gemm<<<(NL + 63) / 64, 256, 0, stream>>>(
        label_embed, label_node_id, Wb, Zrev, Zll);

    // Bucketed CSR build (LDS atomics only, bucket-local writes).
    part_count<<<NCH_TA + NCH_LL + NCH_REV, 256, 0, stream>>>(
        ta_dst, ll_dst, rev_dst, MTa, MLl, MRev);
    part_scan<<<3, 256, 0, stream>>>(MTa, MLl, MRev, bsTa, bsLl, bsRev);
    part_scatter<<<NCH_TA + NCH_LL + NCH_REV, 256, 0, stream>>>(
        ta_src, ta_dst, ll_src, ll_dst, rev_src, rev_dst,
        MTa, MLl, MRev, bsTa, bsLl, bsRev, pTa, pLl, pRev);
    csr_build<<<3 * NBK, 256, 0, stream>>>(
        pTa, bsTa, cntTa, curTa, csrTa,
        pLl, bsLl, cntLl, curLl, csrLl,
        pRev, bsRev, cntRev, curRev, csrRev);

    // rev mean: Zrev -> fp32 permuted, written into the outTitle region.
    agg_rev_kernel<<<NT / 4, 256, 0, stream>>>(
        Zrev, csrRev, cntRev, curRev, out_title);

    // Title GEMM (LDS weights; streams meanRev; writes Zta/outTitle/Zot).
    gemm_title_mfma<<<NT / 64, 256, 0, stream>>>(
        x_title, Wb, b_l_tl, Zta, Zot, out_title);

    // ta + ll means (fused).
    agg_ta_ll_kernel<<<2 * BTA, 256, 0, stream>>>(
        Zta, csrTa, cntTa, curTa, meanTa,
        Zll, csrLl, cntLl, curLl, meanLl);

    // Label GEMM (LDS weights; writes outLabel + Zol over dead Zll).
    gemm_label_mfma<<<(NL + 63) / 64, 256, 0, stream>>>(
        label_embed, label_node_id, Wb, bias_sum, meanTa, meanLl,
        out_label, Zol);

    pred_kernel<<<(ELBL * 32) / 256, 256, 0, stream>>>(
        Zot, out_title, Zol, el_src, el_dst, pred, ELBL);
}